// Round 1
// baseline (154.804 us; speedup 1.0000x reference)
//
#include <hip/hip_runtime.h>
#include <hip/hip_bf16.h>

// out[n,s,d] = sum_{l=0..7} weight[l, x[n,s,l], d]
// N=8, S=2048, L=8, K=1024, D=1024
// One block per (n,s); 256 threads, each handles 4 consecutive d's (float4).
// Index loads are block-uniform -> compiler scalarizes to s_load.
// Weight row reads are contiguous 4 KiB -> fully coalesced dwordx4.

#define NS   (8 * 2048)
#define LVL  8
#define KK   1024
#define DD   1024

__global__ __launch_bounds__(256) void multi_embedding_kernel(
    const int* __restrict__ x,       // (N*S, L) int32
    const float* __restrict__ w,     // (L, K, D) fp32
    float* __restrict__ out)         // (N*S, D) fp32
{
    const int ns = blockIdx.x;       // 0 .. NS-1
    const int d4 = threadIdx.x;      // 0 .. 255 -> float4 slot

    const int* xi = x + (size_t)ns * LVL;

    float4 acc = make_float4(0.f, 0.f, 0.f, 0.f);
#pragma unroll
    for (int l = 0; l < LVL; ++l) {
        const int k = xi[l];
        const float4* row = reinterpret_cast<const float4*>(
            w + ((size_t)l * KK + (size_t)k) * DD);
        const float4 v = row[d4];
        acc.x += v.x;
        acc.y += v.y;
        acc.z += v.z;
        acc.w += v.w;
    }

    reinterpret_cast<float4*>(out + (size_t)ns * DD)[d4] = acc;
}

extern "C" void kernel_launch(void* const* d_in, const int* in_sizes, int n_in,
                              void* d_out, int out_size, void* d_ws, size_t ws_size,
                              hipStream_t stream) {
    const int*   x = (const int*)d_in[0];
    const float* w = (const float*)d_in[1];
    float*     out = (float*)d_out;

    multi_embedding_kernel<<<dim3(NS), dim3(256), 0, stream>>>(x, w, out);
}

// Round 3
// 113.180 us; speedup vs baseline: 1.3678x; 1.3678x over previous
//
#include <hip/hip_runtime.h>
#include <hip/hip_bf16.h>

// out[n,s,d] = sum_{l=0..7} weight[l, x[n,s,l], d]
// N=8, S=2048, L=8, K=1024, D=1024
//
// XCD-locality version: D split into 8 chunks of 128. chunk = blockIdx.x & 7,
// so with round-robin block->XCD dispatch, XCD i only touches
// weight[:, :, 128*i : 128*(i+1)] = 4 MiB = exactly one XCD's L2.
// Gather reads then hit L2 instead of the fabric/LLC.
// Output stored with nontemporal (nt) stores so the 64 MiB write stream
// doesn't evict the weight slice from L2.
//
// Block = 256 threads = 8 ns-rows x 32 lanes; each lane owns one float4
// (16 B) of the 128-float d-chunk -> 512 B contiguous per row segment,
// fully coalesced dwordx4.

#define NS    (8 * 2048)
#define LVL   8
#define KK    1024
#define DD    1024
#define NCH   8                 // d-chunks (== XCD count)
#define DCH   (DD / NCH)        // 128 floats per chunk
#define LANES (DCH / 4)         // 32 lanes per row
#define ROWS  (256 / LANES)     // 8 ns-rows per block

typedef float f32x4 __attribute__((ext_vector_type(4)));

__global__ __launch_bounds__(256) void multi_embedding_kernel(
    const int* __restrict__ x,       // (N*S, L) int32
    const float* __restrict__ w,     // (L, K, D) fp32
    float* __restrict__ out)         // (N*S, D) fp32
{
    const int chunk = blockIdx.x & (NCH - 1);      // -> XCD id (round-robin)
    const int nsg   = blockIdx.x >> 3;             // ns group, 0..2047
    const int lane  = threadIdx.x & (LANES - 1);   // 0..31
    const int row   = threadIdx.x >> 5;            // 0..7
    const int ns    = nsg * ROWS + row;

    // 8 indices for this ns-row (vectorized: two int4 loads)
    const int4* xi4 = reinterpret_cast<const int4*>(x + (size_t)ns * LVL);
    const int4 i0 = xi4[0];
    const int4 i1 = xi4[1];
    int idx[LVL] = { i0.x, i0.y, i0.z, i0.w, i1.x, i1.y, i1.z, i1.w };

    const size_t dbase = (size_t)chunk * DCH;

    f32x4 acc = (f32x4)0.f;
#pragma unroll
    for (int l = 0; l < LVL; ++l) {
        const f32x4* rowp = reinterpret_cast<const f32x4*>(
            w + ((size_t)l * KK + (size_t)idx[l]) * DD + dbase);
        acc += rowp[lane];
    }

    f32x4* op = reinterpret_cast<f32x4*>(out + (size_t)ns * DD + dbase) + lane;
    __builtin_nontemporal_store(acc, op);
}

extern "C" void kernel_launch(void* const* d_in, const int* in_sizes, int n_in,
                              void* d_out, int out_size, void* d_ws, size_t ws_size,
                              hipStream_t stream) {
    const int*   x = (const int*)d_in[0];
    const float* w = (const float*)d_in[1];
    float*     out = (float*)d_out;

    // NS/ROWS groups * NCH chunks = 2048 * 8 = 16384 blocks
    multi_embedding_kernel<<<dim3((NS / ROWS) * NCH), dim3(256), 0, stream>>>(x, w, out);
}

// Round 4
// 108.683 us; speedup vs baseline: 1.4244x; 1.0414x over previous
//
#include <hip/hip_runtime.h>
#include <hip/hip_bf16.h>

// out[n,s,d] = sum_{l=0..7} weight[l, x[n,s,l], d]
// N=8, S=2048, L=8, K=1024, D=1024
//
// XCD-locality: D split into 8 chunks of 128 floats. chunk = blockIdx.x & 7
// -> round-robin block->XCD dispatch keeps each XCD's gather inside its own
// 4 MiB weight slice (fits one XCD L2). FETCH_SIZE ~34 MB confirms (round 3).
//
// This round: index LDS staging (no redundant per-thread global index loads),
// 32 ns-rows per block, 2-row x 8-level unroll -> 16 outstanding dwordx4
// gather loads per wave. nt stores keep the 64 MiB output stream out of L2.

#define NS      (8 * 2048)
#define LVL     8
#define KK      1024
#define DD      1024
#define NCH     8                 // d-chunks (== XCD count)
#define DCH     (DD / NCH)        // 128 floats per chunk
#define ROWSPB  32                // ns rows per block
#define THREADS 256

typedef float f32x4 __attribute__((ext_vector_type(4)));

__global__ __launch_bounds__(THREADS, 4) void multi_embedding_kernel(
    const int* __restrict__ x,       // (N*S, L) int32
    const float* __restrict__ w,     // (L, K, D) fp32
    float* __restrict__ out)         // (N*S, D) fp32
{
    const int chunk = blockIdx.x & (NCH - 1);      // -> XCD id (round-robin)
    const int nsg   = blockIdx.x >> 3;             // 0 .. NS/ROWSPB-1
    const int tid   = threadIdx.x;
    const int ns0   = nsg * ROWSPB;

    // Stage this block's 32 rows x 8 levels of indices: 256 ints = 1 KiB,
    // one coalesced 4 B/lane load per thread.
    __shared__ int sidx[ROWSPB * LVL];
    sidx[tid] = x[(size_t)ns0 * LVL + tid];
    __syncthreads();
    const int4* s4 = reinterpret_cast<const int4*>(sidx);

    const int lane = tid & 31;                     // float4 slot within chunk
    const int rg   = tid >> 5;                     // row group 0..7
    const float* wl = w + (size_t)chunk * DCH + (size_t)lane * 4;

#pragma unroll
    for (int rr = 0; rr < 2; ++rr) {
        const int rowA = rg + (2 * rr + 0) * 8;
        const int rowB = rg + (2 * rr + 1) * 8;

        // broadcast ds_read_b128 x2 per row
        const int4 a0 = s4[rowA * 2], a1 = s4[rowA * 2 + 1];
        const int4 b0 = s4[rowB * 2], b1 = s4[rowB * 2 + 1];
        const int idxA[LVL] = { a0.x, a0.y, a0.z, a0.w, a1.x, a1.y, a1.z, a1.w };
        const int idxB[LVL] = { b0.x, b0.y, b0.z, b0.w, b1.x, b1.y, b1.z, b1.w };

        f32x4 accA = (f32x4)0.f;
        f32x4 accB = (f32x4)0.f;
#pragma unroll
        for (int l = 0; l < LVL; ++l) {
            const f32x4 vA = *reinterpret_cast<const f32x4*>(
                wl + ((size_t)((l << 10) + idxA[l]) << 10));
            const f32x4 vB = *reinterpret_cast<const f32x4*>(
                wl + ((size_t)((l << 10) + idxB[l]) << 10));
            accA += vA;
            accB += vB;
        }

        f32x4* oA = reinterpret_cast<f32x4*>(
            out + (size_t)(ns0 + rowA) * DD + (size_t)chunk * DCH) + lane;
        f32x4* oB = reinterpret_cast<f32x4*>(
            out + (size_t)(ns0 + rowB) * DD + (size_t)chunk * DCH) + lane;
        __builtin_nontemporal_store(accA, oA);
        __builtin_nontemporal_store(accB, oB);
    }
}

extern "C" void kernel_launch(void* const* d_in, const int* in_sizes, int n_in,
                              void* d_out, int out_size, void* d_ws, size_t ws_size,
                              hipStream_t stream) {
    const int*   x = (const int*)d_in[0];
    const float* w = (const float*)d_in[1];
    float*     out = (float*)d_out;

    // NS/ROWSPB groups * NCH chunks = 512 * 8 = 4096 blocks
    multi_embedding_kernel<<<dim3((NS / ROWSPB) * NCH), dim3(THREADS), 0, stream>>>(x, w, out);
}

// Round 5
// 108.576 us; speedup vs baseline: 1.4258x; 1.0010x over previous
//
#include <hip/hip_runtime.h>
#include <hip/hip_bf16.h>
#include <hip/hip_fp16.h>

// out[n,s,d] = sum_{l=0..7} weight[l, x[n,s,l], d]
// N=8, S=2048, L=8, K=1024, D=1024
//
// Two-kernel scheme:
//  1) convert_w: fp32 weight (32 MiB) -> fp16 copy in d_ws (16 MiB).
//  2) gather: XCD-partitioned (chunk = blockIdx&7 -> per-XCD 2 MiB fp16
//     slice in its own L2), fp16 gather (half the L2 bytes / line-requests
//     of fp32), fp16 pk_add accumulate, fp32 nt store.
//
// Gather wave-level: each dwordx4 load = 64 lanes x 16 B covers 4 rows
// (16 lanes x 8 fp16 per row). 16 independent loads in flight per wave
// (2 rows/thread x 8 levels). Indices staged once through LDS.

#define NS      (8 * 2048)
#define LVL     8
#define KK      1024
#define DD      1024
#define NCH     8                 // d-chunks (== XCD count)
#define DCH     (DD / NCH)        // 128 elements per chunk
#define ROWSPB  32                // ns rows per block
#define THREADS 256

typedef _Float16 half8 __attribute__((ext_vector_type(8)));
typedef float    f32x4 __attribute__((ext_vector_type(4)));
typedef float    f32x8 __attribute__((ext_vector_type(8)));

__global__ __launch_bounds__(THREADS) void convert_w_kernel(
    const float* __restrict__ w, _Float16* __restrict__ wh)
{
    const size_t i = ((size_t)blockIdx.x * THREADS + threadIdx.x) * 8;
    const f32x8 v = *reinterpret_cast<const f32x8*>(w + i);
    const half8 h = __builtin_convertvector(v, half8);
    *reinterpret_cast<half8*>(wh + i) = h;
}

__global__ __launch_bounds__(THREADS, 4) void multi_embedding_kernel(
    const int* __restrict__ x,          // (N*S, L) int32
    const _Float16* __restrict__ wh,    // (L, K, D) fp16 (in d_ws)
    float* __restrict__ out)            // (N*S, D) fp32
{
    const int chunk = blockIdx.x & (NCH - 1);      // -> XCD id (round-robin)
    const int nsg   = blockIdx.x >> 3;
    const int tid   = threadIdx.x;
    const int ns0   = nsg * ROWSPB;

    // Stage 32 rows x 8 levels of indices: 256 ints, one 4B load per thread.
    __shared__ int sidx[ROWSPB * LVL];
    sidx[tid] = x[(size_t)ns0 * LVL + tid];
    __syncthreads();
    const int4* s4 = reinterpret_cast<const int4*>(sidx);

    const int lane = tid & 15;       // 8 fp16 (16 B) per lane within chunk
    const int rg   = tid >> 4;       // 0..15
    const _Float16* wl = wh + (size_t)chunk * DCH + (size_t)lane * 8;

    const int rowA = rg;
    const int rowB = rg + 16;

    const int4 a0 = s4[rowA * 2], a1 = s4[rowA * 2 + 1];
    const int4 b0 = s4[rowB * 2], b1 = s4[rowB * 2 + 1];
    const int idxA[LVL] = { a0.x, a0.y, a0.z, a0.w, a1.x, a1.y, a1.z, a1.w };
    const int idxB[LVL] = { b0.x, b0.y, b0.z, b0.w, b1.x, b1.y, b1.z, b1.w };

    // 16 independent 16B loads in flight; fp16 packed accumulation.
    half8 accA = *reinterpret_cast<const half8*>(
        wl + ((size_t)idxA[0] << 10));
    half8 accB = *reinterpret_cast<const half8*>(
        wl + ((size_t)idxB[0] << 10));
#pragma unroll
    for (int l = 1; l < LVL; ++l) {
        const half8 vA = *reinterpret_cast<const half8*>(
            wl + ((size_t)((l << 10) + idxA[l]) << 10));
        const half8 vB = *reinterpret_cast<const half8*>(
            wl + ((size_t)((l << 10) + idxB[l]) << 10));
        accA += vA;
        accB += vB;
    }

    const f32x8 fA = __builtin_convertvector(accA, f32x8);
    const f32x8 fB = __builtin_convertvector(accB, f32x8);
    const f32x4 fA_lo = __builtin_shufflevector(fA, fA, 0, 1, 2, 3);
    const f32x4 fA_hi = __builtin_shufflevector(fA, fA, 4, 5, 6, 7);
    const f32x4 fB_lo = __builtin_shufflevector(fB, fB, 0, 1, 2, 3);
    const f32x4 fB_hi = __builtin_shufflevector(fB, fB, 4, 5, 6, 7);

    float* oA = out + (size_t)(ns0 + rowA) * DD + (size_t)chunk * DCH + (size_t)lane * 8;
    float* oB = out + (size_t)(ns0 + rowB) * DD + (size_t)chunk * DCH + (size_t)lane * 8;
    __builtin_nontemporal_store(fA_lo, reinterpret_cast<f32x4*>(oA));
    __builtin_nontemporal_store(fA_hi, reinterpret_cast<f32x4*>(oA) + 1);
    __builtin_nontemporal_store(fB_lo, reinterpret_cast<f32x4*>(oB));
    __builtin_nontemporal_store(fB_hi, reinterpret_cast<f32x4*>(oB) + 1);
}

extern "C" void kernel_launch(void* const* d_in, const int* in_sizes, int n_in,
                              void* d_out, int out_size, void* d_ws, size_t ws_size,
                              hipStream_t stream) {
    const int*   x = (const int*)d_in[0];
    const float* w = (const float*)d_in[1];
    float*     out = (float*)d_out;
    _Float16*   wh = (_Float16*)d_ws;   // 16 MiB fp16 weight copy

    // 1) fp32 -> fp16 weight conversion: 8M elements / (256*8) = 4096 blocks
    convert_w_kernel<<<dim3((LVL * KK * DD) / (THREADS * 8)), dim3(THREADS), 0, stream>>>(w, wh);

    // 2) gather: NS/ROWSPB groups * NCH chunks = 512 * 8 = 4096 blocks
    multi_embedding_kernel<<<dim3((NS / ROWSPB) * NCH), dim3(THREADS), 0, stream>>>(x, wh, out);
}